// Round 7
// baseline (255.014 us; speedup 1.0000x reference)
//
#include <hip/hip_runtime.h>
#include <hip/hip_bf16.h>

typedef __attribute__((ext_vector_type(4))) float f32x4;
typedef __attribute__((ext_vector_type(8))) short bf16x8;
typedef __attribute__((ext_vector_type(4))) unsigned short u16x4;
typedef __attribute__((ext_vector_type(8))) unsigned short u16x8;

__device__ __forceinline__ unsigned short f2bf(float f) {
    unsigned int u = __builtin_bit_cast(unsigned int, f);
    u += 0x7fffu + ((u >> 16) & 1u);   // RNE; inputs finite
    return (unsigned short)(u >> 16);
}

// swizzle in ushort units: rows are 64 ushorts (128 B); XOR bits 3..5 with row&7
#define SWZ(i) ((i) ^ ((((i) >> 6) & 7) << 3))

// ---------------- transpose+convert: W^T into tiled+swizzled bf16 ----------
__global__ void transpose_cvt(const float* __restrict__ src,
                              unsigned short* __restrict__ dst,
                              int rows, int cols, int ltw) {
    int idx = blockIdx.x * 256 + threadIdx.x;     // idx = n*rows + k
    int n = idx / rows;
    int k = idx - n * rows;
    unsigned short v = f2bf(src[(size_t)k * cols + n]);
    int tw = 1 << ltw;
    int tile = (n >> ltw) * (rows >> 6) + (k >> 6);
    dst[(size_t)tile * (tw * 64) + SWZ((n & (tw - 1)) * 64 + (k & 63))] = v;
}

// ---------------- pack adj -> bf16 tiled+swizzled (row-sequential reads) ---
// Reads adj row-major fully coalesced (4 rows per block, long sequential
// spans); writes 128-B-line chunks of the LDS tile image:
//   tile = (mt*KQC + kql)*32 + p   (128 rows x 64 k = 8192 ushorts each)
//   offset = SWZ((row&127)*64 + (k&63))
__global__ __launch_bounds__(256)
void pack_adj(const float* __restrict__ src, unsigned short* __restrict__ dst,
              int chunk_off, int iters, int KQC) {
    const int t = threadIdx.x;
    const int b = blockIdx.x;                 // 2048 blocks, 4 rows each
    #pragma unroll
    for (int r4 = 0; r4 < 4; ++r4) {
        const int row = b * 4 + r4;
        const int mt = row >> 7, r = row & 127;
        const float* srow = src + (size_t)row * 8192 + chunk_off;
        for (int it = 0; it < iters; ++it) {
            f32x4 v = *reinterpret_cast<const f32x4*>(&srow[it * 1024 + t * 4]);
            u16x4 o = {f2bf(v[0]), f2bf(v[1]), f2bf(v[2]), f2bf(v[3])};
            int tile = (mt * KQC + (it >> 1)) * 32 + (it & 1) * 16 + (t >> 4);
            *reinterpret_cast<u16x4*>(&dst[(size_t)tile * 8192 +
                                           SWZ(r * 64 + (t & 15) * 4)]) = o;
        }
    }
}

// ---------------- small GEMM (K=512): BM=64, BN=128 -----------------------
// EPI 0: D = Tbt (256-wide tiled+swizzled bf16) = acc + epi  [T = input@W1+W2]
// EPI 1: D(f32) = acc + bias[col]  -> writes OUT directly    [out = x@W3 + b]
template<int EPI>
__global__ __launch_bounds__(512, 4)
void gemm_small(const float* __restrict__ A, long lda,
                const unsigned short* __restrict__ Bt,
                int K,
                const float* __restrict__ epi, long lde,
                const float* __restrict__ bias,
                void* __restrict__ Dptr, long ldd) {
    __shared__ unsigned short sA[2][64 * 64];
    __shared__ unsigned short sB[2][128 * 64];

    const int t = threadIdx.x;
    const int l = t & 63;
    const int w = t >> 6;
    const int wm = w >> 2;
    const int wn = w & 3;

    int mt, nt;
    {
        int lin = blockIdx.y * gridDim.x + blockIdx.x;
        int xcd = lin & 7;
        int slot = lin >> 3;
        int ppx = gridDim.y >> 3;
        mt = xcd * ppx + slot / gridDim.x;
        nt = slot % gridDim.x;
    }
    const long m0 = (long)mt * 64;
    const long n0 = (long)nt * 128;
    const int KT = K >> 6;
    const unsigned short* Bblk = Bt + (size_t)nt * KT * 8192;

    f32x4 acc[2][2];
    #pragma unroll
    for (int m = 0; m < 2; ++m)
        #pragma unroll
        for (int n = 0; n < 2; ++n)
            acc[m][n] = {0.f, 0.f, 0.f, 0.f};

    f32x4 aX0, aX1, aY0, aY1;

    auto gll_B = [&](int kt, int buf) {
        const unsigned short* src = Bblk + (size_t)kt * 8192 + t * 8;
        #pragma unroll
        for (int r = 0; r < 2; ++r)
            __builtin_amdgcn_global_load_lds(
                (const __attribute__((address_space(1))) void*)(src + r * 4096),
                (__attribute__((address_space(3))) void*)&sB[buf][r * 4096 + w * 512],
                16, 0, 0);
    };

    auto load_A = [&](int kt, f32x4& a0, f32x4& a1) {
        const float* p0 = &A[(m0 + (t >> 4)) * lda + (long)kt * 64 + ((t & 15) << 2)];
        const float* p1 = p0 + 32 * lda;
        asm volatile("global_load_dwordx4 %0, %2, off\n\t"
                     "global_load_dwordx4 %1, %3, off"
                     : "=&v"(a0), "=&v"(a1)
                     : "v"(p0), "v"(p1)
                     : "memory");
    };

    auto write_A = [&](int buf, const f32x4& a0, const f32x4& a1) {
        int e0 = t * 4;
        u16x4 w0 = {f2bf(a0[0]), f2bf(a0[1]), f2bf(a0[2]), f2bf(a0[3])};
        *reinterpret_cast<u16x4*>(&sA[buf][SWZ(e0)]) = w0;
        int e1 = 2048 + t * 4;
        u16x4 w1 = {f2bf(a1[0]), f2bf(a1[1]), f2bf(a1[2]), f2bf(a1[3])};
        *reinterpret_cast<u16x4*>(&sA[buf][SWZ(e1)]) = w1;
    };

    auto compute = [&](int buf) {
        #pragma unroll
        for (int kk = 0; kk < 2; ++kk) {
            bf16x8 af[2], bfr[2];
            const int kb = kk * 32 + ((l >> 4) << 3);
            #pragma unroll
            for (int m = 0; m < 2; ++m) {
                int row = wm * 32 + m * 16 + (l & 15);
                af[m] = *reinterpret_cast<const bf16x8*>(&sA[buf][SWZ(row * 64 + kb)]);
            }
            #pragma unroll
            for (int n = 0; n < 2; ++n) {
                int col = wn * 32 + n * 16 + (l & 15);
                bfr[n] = *reinterpret_cast<const bf16x8*>(&sB[buf][SWZ(col * 64 + kb)]);
            }
            __builtin_amdgcn_s_setprio(1);
            #pragma unroll
            for (int m = 0; m < 2; ++m)
                #pragma unroll
                for (int n = 0; n < 2; ++n)
                    acc[m][n] = __builtin_amdgcn_mfma_f32_16x16x32_bf16(
                        af[m], bfr[n], acc[m][n], 0, 0, 0);
            __builtin_amdgcn_s_setprio(0);
        }
    };

    gll_B(0, 0);
    load_A(0, aX0, aX1);
    load_A(1, aY0, aY1);
    asm volatile("s_waitcnt vmcnt(2)" ::: "memory");
    __builtin_amdgcn_sched_barrier(0);
    write_A(0, aX0, aX1);
    asm volatile("s_waitcnt lgkmcnt(0)" ::: "memory");
    __builtin_amdgcn_s_barrier();
    __builtin_amdgcn_sched_barrier(0);

    const int nk = K >> 6;   // 8
    for (int p = 0; p + 2 < nk; p += 2) {
        gll_B(p + 1, 1);
        load_A(p + 2, aX0, aX1);
        compute(0);
        asm volatile("s_waitcnt vmcnt(4)" ::: "memory");
        __builtin_amdgcn_sched_barrier(0);
        write_A(1, aY0, aY1);
        asm volatile("s_waitcnt vmcnt(2) lgkmcnt(0)" ::: "memory");
        __builtin_amdgcn_s_barrier();
        __builtin_amdgcn_sched_barrier(0);

        gll_B(p + 2, 0);
        load_A(p + 3, aY0, aY1);
        compute(1);
        asm volatile("s_waitcnt vmcnt(4)" ::: "memory");
        __builtin_amdgcn_sched_barrier(0);
        write_A(0, aX0, aX1);
        asm volatile("s_waitcnt vmcnt(2) lgkmcnt(0)" ::: "memory");
        __builtin_amdgcn_s_barrier();
        __builtin_amdgcn_sched_barrier(0);
    }

    gll_B(nk - 1, 1);
    compute(0);
    asm volatile("s_waitcnt vmcnt(2)" ::: "memory");
    __builtin_amdgcn_sched_barrier(0);
    write_A(1, aY0, aY1);
    asm volatile("s_waitcnt vmcnt(0) lgkmcnt(0)" ::: "memory");
    __builtin_amdgcn_s_barrier();
    __builtin_amdgcn_sched_barrier(0);
    compute(1);

    const int jrow = (l >> 4) * 4;
    #pragma unroll
    for (int m = 0; m < 2; ++m) {
        const long row = m0 + wm * 32 + m * 16 + jrow;
        #pragma unroll
        for (int n = 0; n < 2; ++n) {
            const long col = n0 + wn * 32 + n * 16 + (l & 15);
            f32x4 v = acc[m][n];
            if constexpr (EPI == 0) {
                u16x4 o;
                #pragma unroll
                for (int j = 0; j < 4; ++j)
                    o[j] = f2bf(v[j] + epi[(row + j) * lde + col]);
                int tile = ((int)col >> 8) * 128 + ((int)row >> 6);
                int idx = ((int)col & 255) * 64 + ((int)row & 63);
                *reinterpret_cast<u16x4*>(
                    &((unsigned short*)Dptr)[(size_t)tile * 16384 + SWZ(idx)]) = o;
            } else {
                float b = bias[col];
                #pragma unroll
                for (int j = 0; j < 4; ++j)
                    ((float*)Dptr)[(row + j) * ldd + col] = v[j] + b;
            }
        }
    }
}

// ---------------- big GEMM chunk: out += adjchunk @ Tchunk ----------------
// BM=128, BN=256, all-global_load_lds, double-buffered, counted vmcnt.
// A_bt: [mt(64)][kql(KQC)][p(32)] tiles of 128x64 bf16 (8192 ushorts, SWZ'd)
// Bt  : 256-wide tiles (16384 ushorts), row index = nt*128 + cbase + kql*32 + p
__global__ __launch_bounds__(512, 1)
void gemm_big(const unsigned short* __restrict__ Abt,
              const unsigned short* __restrict__ Bt,
              float* __restrict__ Out,
              int cbase, int KQC) {
    __shared__ unsigned short sA[2][128 * 64];   // 2 x 16 KB
    __shared__ unsigned short sB[2][256 * 64];   // 2 x 32 KB

    const int t = threadIdx.x;
    const int l = t & 63;
    const int w = t >> 6;
    const int wm = w & 1;        // 2 m-waves (64 rows)
    const int wn = w >> 1;       // 4 n-waves (64 cols)

    // XCD map: slot -> (kql, mpart); both nt of each mt co-XCD (L2 A sharing),
    // per-XCD B working set = 2 MB (L2-resident).
    const int lin = blockIdx.x;
    const int slot = lin & 7;
    const int idx = lin >> 3;
    const int kql = slot & (KQC - 1);
    const int mpart = slot >> (KQC - 1);     // KQC=2 -> >>1 ; KQC=1 -> >>0
    const int nt = idx & 1;
    const int mt = mpart * 8 * KQC + (idx >> 1);

    const unsigned short* Ab = Abt + (size_t)(mt * KQC + kql) * 32 * 8192;
    const int ktb = nt * 128 + cbase + kql * 32;

    f32x4 acc[4][4];
    #pragma unroll
    for (int mi = 0; mi < 4; ++mi)
        #pragma unroll
        for (int ni = 0; ni < 4; ++ni)
            acc[mi][ni] = {0.f, 0.f, 0.f, 0.f};

    auto gll_AB = [&](int p, int buf) {
        const unsigned short* sa = Ab + (size_t)p * 8192 + t * 8;
        #pragma unroll
        for (int r = 0; r < 2; ++r)
            __builtin_amdgcn_global_load_lds(
                (const __attribute__((address_space(1))) void*)(sa + r * 4096),
                (__attribute__((address_space(3))) void*)&sA[buf][r * 4096 + w * 512],
                16, 0, 0);
        const unsigned short* sb = Bt + (size_t)(ktb + p) * 16384 + t * 8;
        #pragma unroll
        for (int r = 0; r < 4; ++r)
            __builtin_amdgcn_global_load_lds(
                (const __attribute__((address_space(1))) void*)(sb + r * 4096),
                (__attribute__((address_space(3))) void*)&sB[buf][r * 4096 + w * 512],
                16, 0, 0);
    };

    auto compute = [&](int buf) {
        #pragma unroll
        for (int kk = 0; kk < 2; ++kk) {
            const int kb = kk * 32 + ((l >> 4) << 3);
            bf16x8 af[4], bf[4];
            #pragma unroll
            for (int mi = 0; mi < 4; ++mi) {
                int row = wm * 64 + mi * 16 + (l & 15);
                af[mi] = *reinterpret_cast<const bf16x8*>(&sA[buf][SWZ(row * 64 + kb)]);
            }
            #pragma unroll
            for (int ni = 0; ni < 4; ++ni) {
                int col = wn * 64 + ni * 16 + (l & 15);
                bf[ni] = *reinterpret_cast<const bf16x8*>(&sB[buf][SWZ(col * 64 + kb)]);
            }
            __builtin_amdgcn_s_setprio(1);
            #pragma unroll
            for (int mi = 0; mi < 4; ++mi)
                #pragma unroll
                for (int ni = 0; ni < 4; ++ni)
                    acc[mi][ni] = __builtin_amdgcn_mfma_f32_16x16x32_bf16(
                        af[mi], bf[ni], acc[mi][ni], 0, 0, 0);
            __builtin_amdgcn_s_setprio(0);
        }
    };

    gll_AB(0, 0);                                   // 6 outstanding
    for (int p = 0; p < 31; ++p) {
        gll_AB(p + 1, (p + 1) & 1);                 // 12 outstanding
        asm volatile("s_waitcnt vmcnt(6)" ::: "memory");   // tile p landed
        __builtin_amdgcn_sched_barrier(0);
        __builtin_amdgcn_s_barrier();
        __builtin_amdgcn_sched_barrier(0);
        compute(p & 1);
        __builtin_amdgcn_s_barrier();
    }
    asm volatile("s_waitcnt vmcnt(0)" ::: "memory");
    __builtin_amdgcn_sched_barrier(0);
    __builtin_amdgcn_s_barrier();
    __builtin_amdgcn_sched_barrier(0);
    compute(1);

    // epilogue: atomic accumulate into pre-filled Out
    #pragma unroll
    for (int mi = 0; mi < 4; ++mi) {
        const long row0 = (long)mt * 128 + wm * 64 + mi * 16 + ((l >> 4) << 2);
        #pragma unroll
        for (int ni = 0; ni < 4; ++ni) {
            const int col = nt * 256 + wn * 64 + ni * 16 + (l & 15);
            #pragma unroll
            for (int j = 0; j < 4; ++j)
                unsafeAtomicAdd(&Out[(row0 + j) * 512 + col], acc[mi][ni][j]);
        }
    }
}

extern "C" void kernel_launch(void* const* d_in, const int* in_sizes, int n_in,
                              void* d_out, int out_size, void* d_ws, size_t ws_size,
                              hipStream_t stream) {
    const float* input  = (const float*)d_in[0];   // 8192 x 512
    const float* adj    = (const float*)d_in[1];   // 8192 x 8192
    const float* x      = (const float*)d_in[2];   // 8192 x 512
    const float* weight = (const float*)d_in[3];   // 9216 x 512
    const float* bias   = (const float*)d_in[4];   // 512

    const int N = 8192, IN_F = 512, NFEAT = 512, OUT_F = 512;
    float* out = (float*)d_out;

    // chunking: NC=2 (KQC=2, 64 MB scratch) if ws allows, else NC=4 (KQC=1)
    const size_t fixedBytes = (size_t)512 * 8192 * 2 + 2 * (size_t)512 * 512 * 2;
    int NC = (ws_size >= (size_t)8192 * 4096 * 2 + fixedBytes) ? 2 : 4;
    const int KQC = (NC == 2) ? 2 : 1;
    const int chunkK = 8192 / NC;
    const size_t chunkBytes = (size_t)8192 * chunkK * 2;

    unsigned short* Abt = (unsigned short*)d_ws;
    unsigned short* Tbt = (unsigned short*)((char*)d_ws + chunkBytes);
    unsigned short* W1t = Tbt + (size_t)OUT_F * N;
    unsigned short* W3t = W1t + (size_t)OUT_F * IN_F;

    transpose_cvt<<<dim3((IN_F * OUT_F) / 256), dim3(256), 0, stream>>>(
        weight, W1t, IN_F, OUT_F, 7);
    transpose_cvt<<<dim3((NFEAT * OUT_F) / 256), dim3(256), 0, stream>>>(
        weight + (size_t)(IN_F + N) * OUT_F, W3t, NFEAT, OUT_F, 7);

    dim3 grid(OUT_F / 128, N / 64);   // (4, 128) = 512 blocks

    // out = x @ W3 + bias   (pre-fill for big-GEMM atomics)
    gemm_small<1><<<grid, 512, 0, stream>>>(
        x, (long)NFEAT, W3t, NFEAT,
        nullptr, 0, bias,
        out, (long)OUT_F);

    // Tbt = (input @ W1 + W2) in 256-wide tiled+swizzled bf16
    gemm_small<0><<<grid, 512, 0, stream>>>(
        input, (long)IN_F, W1t, IN_F,
        weight + (size_t)IN_F * OUT_F, (long)OUT_F, nullptr,
        Tbt, 0);

    // out += adj @ T, chunk by chunk (pack -> gemm, stream-serialized)
    const int nBlocks = 64 * 2 * KQC;             // 256 (NC=2) or 128 (NC=4)
    for (int c = 0; c < NC; ++c) {
        pack_adj<<<dim3(2048), dim3(256), 0, stream>>>(
            adj, Abt, c * chunkK, chunkK / 1024, KQC);
        gemm_big<<<dim3(nBlocks), dim3(512), 0, stream>>>(
            Abt, Tbt, out, c * (128 / NC), KQC);
    }
}

// Round 8
// 164.510 us; speedup vs baseline: 1.5501x; 1.5501x over previous
//
#include <hip/hip_runtime.h>
#include <hip/hip_bf16.h>

typedef __attribute__((ext_vector_type(4))) float f32x4;
typedef __attribute__((ext_vector_type(8))) short bf16x8;
typedef __attribute__((ext_vector_type(4))) unsigned short u16x4;
typedef __attribute__((ext_vector_type(8))) unsigned short u16x8;

__device__ __forceinline__ unsigned short f2bf(float f) {
    unsigned int u = __builtin_bit_cast(unsigned int, f);
    u += 0x7fffu + ((u >> 16) & 1u);   // RNE; inputs finite
    return (unsigned short)(u >> 16);
}

// swizzle in ushort units: rows are 64 ushorts (128 B); XOR bits 3..5 with row&7
#define SWZ(i) ((i) ^ ((((i) >> 6) & 7) << 3))

// ---------------- transpose+convert: W^T into tiled+swizzled bf16 ----------
// 128-wide tiles: tile = (n>>7)*(rows/64) + (k>>6); idx SWZ((n&127)*64+(k&63))
__global__ void transpose_cvt(const float* __restrict__ src,
                              unsigned short* __restrict__ dst,
                              int rows, int cols) {
    int idx = blockIdx.x * 256 + threadIdx.x;     // idx = n*rows + k
    int n = idx / rows;
    int k = idx - n * rows;
    unsigned short v = f2bf(src[(size_t)k * cols + n]);
    int tile = (n >> 7) * (rows >> 6) + (k >> 6);
    dst[(size_t)tile * 8192 + SWZ((n & 127) * 64 + (k & 63))] = v;
}

// ---------------- small GEMM (K=512): BM=64, BN=128 -----------------------
// EPI 0: D = Tbt (128-wide tiled+swizzled bf16) = acc + epi  [T = input@W1+W2]
// EPI 1: D(f32) = acc + bias[col]  -> writes OUT directly    [out = x@W3 + b]
template<int EPI>
__global__ __launch_bounds__(512, 4)
void gemm_small(const float* __restrict__ A, long lda,
                const unsigned short* __restrict__ Bt,
                int K,
                const float* __restrict__ epi, long lde,
                const float* __restrict__ bias,
                void* __restrict__ Dptr, long ldd) {
    __shared__ unsigned short sA[2][64 * 64];
    __shared__ unsigned short sB[2][128 * 64];

    const int t = threadIdx.x;
    const int l = t & 63;
    const int w = t >> 6;
    const int wm = w >> 2;
    const int wn = w & 3;

    int mt, nt;
    {
        int lin = blockIdx.y * gridDim.x + blockIdx.x;
        int xcd = lin & 7;
        int slot = lin >> 3;
        int ppx = gridDim.y >> 3;
        mt = xcd * ppx + slot / gridDim.x;
        nt = slot % gridDim.x;
    }
    const long m0 = (long)mt * 64;
    const long n0 = (long)nt * 128;
    const int KT = K >> 6;
    const unsigned short* Bblk = Bt + (size_t)nt * KT * 8192;

    f32x4 acc[2][2];
    #pragma unroll
    for (int m = 0; m < 2; ++m)
        #pragma unroll
        for (int n = 0; n < 2; ++n)
            acc[m][n] = {0.f, 0.f, 0.f, 0.f};

    f32x4 aX0, aX1, aY0, aY1;

    auto gll_B = [&](int kt, int buf) {
        const unsigned short* src = Bblk + (size_t)kt * 8192 + t * 8;
        #pragma unroll
        for (int r = 0; r < 2; ++r)
            __builtin_amdgcn_global_load_lds(
                (const __attribute__((address_space(1))) void*)(src + r * 4096),
                (__attribute__((address_space(3))) void*)&sB[buf][r * 4096 + w * 512],
                16, 0, 0);
    };

    auto load_A = [&](int kt, f32x4& a0, f32x4& a1) {
        const float* p0 = &A[(m0 + (t >> 4)) * lda + (long)kt * 64 + ((t & 15) << 2)];
        const float* p1 = p0 + 32 * lda;
        asm volatile("global_load_dwordx4 %0, %2, off\n\t"
                     "global_load_dwordx4 %1, %3, off"
                     : "=&v"(a0), "=&v"(a1)
                     : "v"(p0), "v"(p1)
                     : "memory");
    };

    auto write_A = [&](int buf, const f32x4& a0, const f32x4& a1) {
        int e0 = t * 4;
        u16x4 w0 = {f2bf(a0[0]), f2bf(a0[1]), f2bf(a0[2]), f2bf(a0[3])};
        *reinterpret_cast<u16x4*>(&sA[buf][SWZ(e0)]) = w0;
        int e1 = 2048 + t * 4;
        u16x4 w1 = {f2bf(a1[0]), f2bf(a1[1]), f2bf(a1[2]), f2bf(a1[3])};
        *reinterpret_cast<u16x4*>(&sA[buf][SWZ(e1)]) = w1;
    };

    auto compute = [&](int buf) {
        #pragma unroll
        for (int kk = 0; kk < 2; ++kk) {
            bf16x8 af[2], bfr[2];
            const int kb = kk * 32 + ((l >> 4) << 3);
            #pragma unroll
            for (int m = 0; m < 2; ++m) {
                int row = wm * 32 + m * 16 + (l & 15);
                af[m] = *reinterpret_cast<const bf16x8*>(&sA[buf][SWZ(row * 64 + kb)]);
            }
            #pragma unroll
            for (int n = 0; n < 2; ++n) {
                int col = wn * 32 + n * 16 + (l & 15);
                bfr[n] = *reinterpret_cast<const bf16x8*>(&sB[buf][SWZ(col * 64 + kb)]);
            }
            __builtin_amdgcn_s_setprio(1);
            #pragma unroll
            for (int m = 0; m < 2; ++m)
                #pragma unroll
                for (int n = 0; n < 2; ++n)
                    acc[m][n] = __builtin_amdgcn_mfma_f32_16x16x32_bf16(
                        af[m], bfr[n], acc[m][n], 0, 0, 0);
            __builtin_amdgcn_s_setprio(0);
        }
    };

    gll_B(0, 0);
    load_A(0, aX0, aX1);
    load_A(1, aY0, aY1);
    asm volatile("s_waitcnt vmcnt(2)" ::: "memory");
    __builtin_amdgcn_sched_barrier(0);
    write_A(0, aX0, aX1);
    asm volatile("s_waitcnt lgkmcnt(0)" ::: "memory");
    __builtin_amdgcn_s_barrier();
    __builtin_amdgcn_sched_barrier(0);

    const int nk = K >> 6;   // 8
    for (int p = 0; p + 2 < nk; p += 2) {
        gll_B(p + 1, 1);
        load_A(p + 2, aX0, aX1);
        compute(0);
        asm volatile("s_waitcnt vmcnt(4)" ::: "memory");
        __builtin_amdgcn_sched_barrier(0);
        write_A(1, aY0, aY1);
        asm volatile("s_waitcnt vmcnt(2) lgkmcnt(0)" ::: "memory");
        __builtin_amdgcn_s_barrier();
        __builtin_amdgcn_sched_barrier(0);

        gll_B(p + 2, 0);
        load_A(p + 3, aY0, aY1);
        compute(1);
        asm volatile("s_waitcnt vmcnt(4)" ::: "memory");
        __builtin_amdgcn_sched_barrier(0);
        write_A(0, aX0, aX1);
        asm volatile("s_waitcnt vmcnt(2) lgkmcnt(0)" ::: "memory");
        __builtin_amdgcn_s_barrier();
        __builtin_amdgcn_sched_barrier(0);
    }

    gll_B(nk - 1, 1);
    compute(0);
    asm volatile("s_waitcnt vmcnt(2)" ::: "memory");
    __builtin_amdgcn_sched_barrier(0);
    write_A(1, aY0, aY1);
    asm volatile("s_waitcnt vmcnt(0) lgkmcnt(0)" ::: "memory");
    __builtin_amdgcn_s_barrier();
    __builtin_amdgcn_sched_barrier(0);
    compute(1);

    const int jrow = (l >> 4) * 4;
    #pragma unroll
    for (int m = 0; m < 2; ++m) {
        const long row = m0 + wm * 32 + m * 16 + jrow;
        #pragma unroll
        for (int n = 0; n < 2; ++n) {
            const long col = n0 + wn * 32 + n * 16 + (l & 15);
            f32x4 v = acc[m][n];
            if constexpr (EPI == 0) {
                u16x4 o;
                #pragma unroll
                for (int j = 0; j < 4; ++j)
                    o[j] = f2bf(v[j] + epi[(row + j) * lde + col]);
                int tile = ((int)col >> 7) * (int)ldd + ((int)row >> 6);
                int idx = ((int)col & 127) * 64 + ((int)row & 63);
                *reinterpret_cast<u16x4*>(
                    &((unsigned short*)Dptr)[(size_t)tile * 8192 + SWZ(idx)]) = o;
            } else {
                float b = bias[col];
                #pragma unroll
                for (int j = 0; j < 4; ++j)
                    ((float*)Dptr)[(row + j) * ldd + col] = v[j] + b;
            }
        }
    }
}

// ---------------- big GEMM: out += adj @ T ---------------------------------
// BM=128, BN=128, BK=64; 512 blocks = 64mt x 4nt x 2kq; K/block=4096 (64 ph).
// XCD map: xcd = lin&7 hosts mt chunk [xcd*8, xcd*8+8); all 8 (nt,kq) blocks
// of one mt are co-XCD -> adj slab L3-fetched once, nt-sharers hit L2.
__global__ __launch_bounds__(512, 4)
void gemm_big(const float* __restrict__ A,            // adj 8192x8192 f32
              const unsigned short* __restrict__ Bt,  // Tbt [4][128][8192]
              float* __restrict__ Out) {              // 8192x512 (pre-filled)
    __shared__ unsigned short sA[2][128 * 64];   // 2 x 16 KB
    __shared__ unsigned short sB[2][128 * 64];   // 2 x 16 KB

    const int t = threadIdx.x;
    const int l = t & 63;
    const int w = t >> 6;
    const int wm = w & 1;        // 2 m-waves (64 rows)
    const int wn = w >> 1;       // 4 n-waves (32 cols)

    const int lin = blockIdx.x;          // 0..511
    const int xcd = lin & 7;
    const int idx = lin >> 3;            // 0..63
    const int mt = xcd * 8 + (idx & 7);  // mt chunk per XCD
    const int sub = idx >> 3;            // 0..7
    const int nt = sub >> 1;             // 0..3
    const int kq = sub & 1;              // 0..1

    const long m0 = (long)mt * 128;
    const long k0 = (long)kq * 4096;
    const unsigned short* Bblk = Bt + ((size_t)(nt * 128 + kq * 64)) * 8192;
    constexpr int P = 64;                // phases of BK=64

    f32x4 acc[4][2];
    #pragma unroll
    for (int mi = 0; mi < 4; ++mi)
        #pragma unroll
        for (int ni = 0; ni < 2; ++ni)
            acc[mi][ni] = {0.f, 0.f, 0.f, 0.f};

    f32x4 avX[4], avY[4];    // two named A reg stages (rule #20)

    auto gll_B = [&](int p, int buf) {
        const unsigned short* src = Bblk + (size_t)p * 8192 + t * 8;
        #pragma unroll
        for (int r = 0; r < 2; ++r)
            __builtin_amdgcn_global_load_lds(
                (const __attribute__((address_space(1))) void*)(src + r * 4096),
                (__attribute__((address_space(3))) void*)&sB[buf][r * 4096 + w * 512],
                16, 0, 0);
    };

    auto load_A4 = [&](int p, f32x4* av) {
        #pragma unroll
        for (int j = 0; j < 4; ++j) {
            const float* ptr = A + (m0 + j * 32 + (t >> 4)) * 8192 + k0 +
                               (long)p * 64 + ((t & 15) << 2);
            asm volatile("global_load_dwordx4 %0, %1, off"
                         : "=&v"(av[j]) : "v"(ptr) : "memory");
        }
    };

    auto write_A = [&](int buf, const f32x4* av) {
        #pragma unroll
        for (int j = 0; j < 4; ++j) {
            int e = j * 2048 + t * 4;
            u16x4 wv = {f2bf(av[j][0]), f2bf(av[j][1]), f2bf(av[j][2]), f2bf(av[j][3])};
            *reinterpret_cast<u16x4*>(&sA[buf][SWZ(e)]) = wv;
        }
    };

    auto compute = [&](int buf) {
        #pragma unroll
        for (int kk = 0; kk < 2; ++kk) {
            const int kb = kk * 32 + ((l >> 4) << 3);
            bf16x8 af[4], bfr[2];
            #pragma unroll
            for (int mi = 0; mi < 4; ++mi) {
                int row = wm * 64 + mi * 16 + (l & 15);
                af[mi] = *reinterpret_cast<const bf16x8*>(&sA[buf][SWZ(row * 64 + kb)]);
            }
            #pragma unroll
            for (int ni = 0; ni < 2; ++ni) {
                int col = wn * 32 + ni * 16 + (l & 15);
                bfr[ni] = *reinterpret_cast<const bf16x8*>(&sB[buf][SWZ(col * 64 + kb)]);
            }
            __builtin_amdgcn_s_setprio(1);
            #pragma unroll
            for (int mi = 0; mi < 4; ++mi)
                #pragma unroll
                for (int ni = 0; ni < 2; ++ni)
                    acc[mi][ni] = __builtin_amdgcn_mfma_f32_16x16x32_bf16(
                        af[mi], bfr[ni], acc[mi][ni], 0, 0, 0);
            __builtin_amdgcn_s_setprio(0);
        }
    };

    // ---- prologue: issue order B(0)[2], A(0)[4], A(1)[4] ----
    gll_B(0, 0);
    load_A4(0, avX);
    load_A4(1, avY);
    asm volatile("s_waitcnt vmcnt(4)" ::: "memory");   // B(0)+A(0) landed
    __builtin_amdgcn_sched_barrier(0);
    write_A(0, avX);
    asm volatile("s_waitcnt lgkmcnt(0)" ::: "memory");
    __builtin_amdgcn_s_barrier();
    __builtin_amdgcn_sched_barrier(0);

    // steady: entering phase p, sA/sB[p&1] valid, other-stage regs = A(p+1),
    // 4 outstanding (A(p+1)).
    for (int p = 0; p < P - 2; p += 2) {
        // even phase p: write avY=A(p+1), load avX=A(p+2)
        gll_B(p + 1, 1);
        load_A4(p + 2, avX);                 // outstanding: 4+2+4 = 10
        asm volatile("s_waitcnt vmcnt(6)" ::: "memory");   // A(p+1) landed
        __builtin_amdgcn_sched_barrier(0);
        write_A(1, avY);
        compute(0);
        asm volatile("s_waitcnt vmcnt(4) lgkmcnt(0)" ::: "memory"); // B(p+1) in
        __builtin_amdgcn_s_barrier();
        __builtin_amdgcn_sched_barrier(0);

        // odd phase p+1: write avX=A(p+2), load avY=A(p+3)
        gll_B(p + 2, 0);
        load_A4(p + 3, avY);
        asm volatile("s_waitcnt vmcnt(6)" ::: "memory");
        __builtin_amdgcn_sched_barrier(0);
        write_A(0, avX);
        compute(1);
        asm volatile("s_waitcnt vmcnt(4) lgkmcnt(0)" ::: "memory");
        __builtin_amdgcn_s_barrier();
        __builtin_amdgcn_sched_barrier(0);
    }

    // phase P-2 (even): avY = A(P-1) pending; no more A loads
    gll_B(P - 1, 1);                          // outstanding: A(P-1)4 + B2 = 6
    asm volatile("s_waitcnt vmcnt(2)" ::: "memory");   // A(P-1) landed
    __builtin_amdgcn_sched_barrier(0);
    write_A(1, avY);
    compute(0);
    asm volatile("s_waitcnt vmcnt(0) lgkmcnt(0)" ::: "memory");
    __builtin_amdgcn_s_barrier();
    __builtin_amdgcn_sched_barrier(0);

    // phase P-1
    compute(1);

    // epilogue: atomic accumulate into pre-filled Out
    #pragma unroll
    for (int mi = 0; mi < 4; ++mi) {
        const long row0 = m0 + wm * 64 + mi * 16 + ((l >> 4) << 2);
        #pragma unroll
        for (int ni = 0; ni < 2; ++ni) {
            const int col = nt * 128 + wn * 32 + ni * 16 + (l & 15);
            #pragma unroll
            for (int j = 0; j < 4; ++j)
                unsafeAtomicAdd(&Out[(row0 + j) * 512 + col], acc[mi][ni][j]);
        }
    }
}

extern "C" void kernel_launch(void* const* d_in, const int* in_sizes, int n_in,
                              void* d_out, int out_size, void* d_ws, size_t ws_size,
                              hipStream_t stream) {
    const float* input  = (const float*)d_in[0];   // 8192 x 512
    const float* adj    = (const float*)d_in[1];   // 8192 x 8192
    const float* x      = (const float*)d_in[2];   // 8192 x 512
    const float* weight = (const float*)d_in[3];   // 9216 x 512
    const float* bias   = (const float*)d_in[4];   // 512

    const int N = 8192, IN_F = 512, NFEAT = 512, OUT_F = 512;
    float* out = (float*)d_out;

    // workspace (~9.5 MB): Tbt [4 ntile][128 ktile][8192], W1t/W3t [4][8][8192]
    unsigned short* Tbt = (unsigned short*)d_ws;
    unsigned short* W1t = Tbt + (size_t)OUT_F * N;
    unsigned short* W3t = W1t + (size_t)OUT_F * IN_F;

    transpose_cvt<<<dim3((IN_F * OUT_F) / 256), dim3(256), 0, stream>>>(
        weight, W1t, IN_F, OUT_F);
    transpose_cvt<<<dim3((NFEAT * OUT_F) / 256), dim3(256), 0, stream>>>(
        weight + (size_t)(IN_F + N) * OUT_F, W3t, NFEAT, OUT_F);

    dim3 grid(OUT_F / 128, N / 64);   // (4, 128) = 512 blocks

    // out = x @ W3 + bias   (pre-fill for big-GEMM atomics)
    gemm_small<1><<<grid, 512, 0, stream>>>(
        x, (long)NFEAT, W3t, NFEAT,
        nullptr, 0, bias,
        out, (long)OUT_F);

    // Tbt = (input @ W1 + W2) in 128-wide tiled+swizzled bf16 (ldd = K-tiles)
    gemm_small<0><<<grid, 512, 0, stream>>>(
        input, (long)IN_F, W1t, IN_F,
        weight + (size_t)IN_F * OUT_F, (long)OUT_F, nullptr,
        Tbt, (long)(N / 64));

    // out += adj @ T
    gemm_big<<<dim3(512), dim3(512), 0, stream>>>(adj, Tbt, out);
}